// Round 2
// baseline (671.153 us; speedup 1.0000x reference)
//
#include <hip/hip_runtime.h>

#define T_DIM 8
#define M_DIM 16384
#define K_DIM 128
#define N_DIM 1024

typedef __attribute__((ext_vector_type(8))) short bf16x8_t;
typedef __attribute__((ext_vector_type(4))) float f32x4_t;

__device__ __forceinline__ unsigned short f2bf(float f) {
  unsigned int v;
  __builtin_memcpy(&v, &f, 4);
  v += 0x7FFFu + ((v >> 16) & 1u);  // round-to-nearest-even
  return (unsigned short)(v >> 16);
}

// tanh-form gelu: g = x * t/(t+1), t = exp2(2*sqrt(2/pi)*log2(e)*(x+0.044715 x^3))
// max abs err vs exact erf-gelu ~3e-4. Clamp the nonlinear arg so t stays finite.
__device__ __forceinline__ float gelu_tanh(float x) {
  float xc = fminf(fmaxf(x, -8.f), 8.f);
  float y = 2.3022144f * __builtin_fmaf(0.044715f * xc * xc, xc, xc);
  float t = __builtin_amdgcn_exp2f(y);
  return x * t * __builtin_amdgcn_rcpf(t + 1.0f);
}

// W[t][k][n] fp32 -> WT[t][n][k] bf16, so the GEMM's B operand is k-contiguous.
__global__ __launch_bounds__(256) void transpose_w(
    const float* __restrict__ W, unsigned short* __restrict__ WT) {
  __shared__ __align__(16) unsigned short tile[64][72];
  int b = blockIdx.x;  // 8 t * 2 kt * 16 nt = 256 blocks
  int t = b >> 5;
  int r = b & 31;
  int kt = r >> 4;  // 0..1
  int nt = r & 15;  // 0..15
  int tid = threadIdx.x;
  const float* src =
      W + (size_t)t * (K_DIM * N_DIM) + (size_t)(kt * 64) * N_DIM + nt * 64;
#pragma unroll
  for (int it = 0; it < 4; ++it) {
    int li = it * 256 + tid;  // 0..1023
    int k = li >> 4;          // 0..63
    int c = li & 15;          // 0..15 (4-float chunks)
    float4 v = *(const float4*)(src + (size_t)k * N_DIM + c * 4);
    unsigned short u[4] = {f2bf(v.x), f2bf(v.y), f2bf(v.z), f2bf(v.w)};
    *(uint2*)&tile[k][c * 4] = *(const uint2*)u;  // 8 B, aligned (row stride 144 B)
  }
  __syncthreads();
  unsigned short* dst =
      WT + (size_t)t * (N_DIM * K_DIM) + (size_t)(nt * 64) * K_DIM + kt * 64;
#pragma unroll
  for (int it = 0; it < 2; ++it) {
    int li = it * 256 + tid;  // 0..511
    int n = li >> 3;          // 0..63
    int ck = li & 7;          // 0..7
    __align__(16) unsigned short tmp[8];
#pragma unroll
    for (int j = 0; j < 8; ++j) tmp[j] = tile[ck * 8 + j][n];
    *(uint4*)(dst + (size_t)n * K_DIM + ck * 8) = *(const uint4*)tmp;
  }
}

// Per block: 128x128 output tile of batch t. 4 waves in 2x2, each 64x64 via
// 4x4 grid of 16x16x32 bf16 MFMAs. K=128 in two BK=64 LDS stages.
// A is fp32 in HBM, converted to bf16 while staging into LDS.
__global__ __launch_bounds__(256, 2) void gemm_bias_gelu(
    const float* __restrict__ A,             // [T][M][K] fp32
    const unsigned short* __restrict__ WT,   // [T][N][K] bf16
    const float* __restrict__ bias,          // [T][N] fp32
    float* __restrict__ O) {                 // [T][M][N] fp32
  constexpr int BM = 128, BN = 128, BK = 64;
  constexpr int LDT = 72;  // 64 + 8 pad halves -> at most 2-way bank alias (free)
  __shared__ __align__(16) unsigned short smem[2 * 128 * LDT];  // 36864 B
  unsigned short* sA = smem;
  unsigned short* sB = smem + 128 * LDT;

  // nt FASTEST: the 8 blocks sharing one A-tile are dispatch-adjacent, so
  // A's 8x logical reuse hits L3 instead of re-fetching 512 MiB from HBM.
  int bid = blockIdx.x;        // 8192 = 8 t * 128 mt * 8 nt
  int t = bid >> 10;
  int mt = (bid >> 3) & 127;   // 0..127
  int nt = bid & 7;            // 0..7

  int tid = threadIdx.x;
  int lane = tid & 63;
  int wave = tid >> 6;
  int wm = wave & 1;
  int wn = wave >> 1;
  int qk = lane >> 4;  // 0..3
  int lr = lane & 15;  // 0..15

  const float* Ag =
      A + (size_t)t * ((size_t)M_DIM * K_DIM) + (size_t)(mt * BM) * K_DIM;
  const unsigned short* Bg =
      WT + (size_t)t * (N_DIM * K_DIM) + (size_t)(nt * BN) * K_DIM;

  f32x4_t acc[4][4];
#pragma unroll
  for (int i = 0; i < 4; ++i)
#pragma unroll
    for (int j = 0; j < 4; ++j) acc[i][j] = (f32x4_t){0.f, 0.f, 0.f, 0.f};

#pragma unroll
  for (int ks = 0; ks < 2; ++ks) {
    if (ks) __syncthreads();  // prior stage's LDS reads done before overwrite
    // A: fp32 load + convert. 128 rows x 16 chunks(4 floats) = 2048 -> 8 iters
#pragma unroll
    for (int it = 0; it < 8; ++it) {
      int li = it * 256 + tid;
      int row = li >> 4;   // 0..127
      int c = li & 15;     // 0..15
      float4 va = *(const float4*)(Ag + (size_t)row * K_DIM + ks * BK + c * 4);
      unsigned short u[4] = {f2bf(va.x), f2bf(va.y), f2bf(va.z), f2bf(va.w)};
      *(uint2*)&sA[row * LDT + c * 4] = *(const uint2*)u;
    }
    // B: already bf16. 128 rows x 8 chunks(8 halves) = 1024 -> 4 iters
#pragma unroll
    for (int it = 0; it < 4; ++it) {
      int li = it * 256 + tid;
      int row = li >> 3;   // 0..127
      int c = li & 7;      // 0..7
      uint4 vb = *(const uint4*)(Bg + (size_t)row * K_DIM + ks * BK + c * 8);
      *(uint4*)&sB[row * LDT + c * 8] = vb;
    }
    __syncthreads();
#pragma unroll
    for (int kk = 0; kk < 2; ++kk) {
      bf16x8_t af[4], bfv[4];
#pragma unroll
      for (int i = 0; i < 4; ++i) {
        int am = wm * 64 + i * 16 + lr;
        af[i] = *(const bf16x8_t*)&sA[am * LDT + kk * 32 + qk * 8];
        int bn = wn * 64 + i * 16 + lr;
        bfv[i] = *(const bf16x8_t*)&sB[bn * LDT + kk * 32 + qk * 8];
      }
#pragma unroll
      for (int i = 0; i < 4; ++i)
#pragma unroll
        for (int j = 0; j < 4; ++j)
          acc[i][j] = __builtin_amdgcn_mfma_f32_16x16x32_bf16(af[i], bfv[j],
                                                              acc[i][j], 0, 0, 0);
    }
  }

  // ---- epilogue: bias + gelu in registers, direct fp32 stores.
  // Per store instr: lanes = 4 rows x 16 consecutive n -> four dense 64B segments.
  float bv[4];
#pragma unroll
  for (int j = 0; j < 4; ++j)
    bv[j] = bias[t * N_DIM + nt * BN + wn * 64 + j * 16 + lr];

  float* Og = O + (size_t)t * ((size_t)M_DIM * N_DIM) +
              (size_t)(mt * BM) * N_DIM + nt * BN;
#pragma unroll
  for (int i = 0; i < 4; ++i) {
#pragma unroll
    for (int j = 0; j < 4; ++j) {
#pragma unroll
      for (int rr = 0; rr < 4; ++rr) {
        // C/D layout: col = lane&15, row = (lane>>4)*4 + rr  [m89/m91]
        float x = acc[i][j][rr] + bv[j];
        float g = gelu_tanh(x);
        int m = wm * 64 + i * 16 + qk * 4 + rr;
        int n = wn * 64 + j * 16 + lr;
        Og[(size_t)m * N_DIM + n] = g;
      }
    }
  }
}

extern "C" void kernel_launch(void* const* d_in, const int* in_sizes, int n_in,
                              void* d_out, int out_size, void* d_ws, size_t ws_size,
                              hipStream_t stream) {
  const float* A = (const float*)d_in[0];     // inputs  [8,1,16384,128] fp32
  const float* W = (const float*)d_in[1];     // weights [8,1,128,1024] fp32
  const float* bias = (const float*)d_in[2];  // biases  [8,1,1,1024] fp32
  float* O = (float*)d_out;                   // [8,1,16384,1024] fp32
  unsigned short* WT = (unsigned short*)d_ws; // 2 MiB scratch: W^T in bf16

  transpose_w<<<256, 256, 0, stream>>>(W, WT);
  gemm_bias_gelu<<<8192, 256, 0, stream>>>(A, WT, bias, O);
}